// Round 12
// baseline (895.940 us; speedup 1.0000x reference)
//
#include <hip/hip_runtime.h>
#include <math.h>

#define N_PTS 8192
#define ICP_STEPS 21      // STEPLIM + 1 scan iterations
#define ICP_TOL 1e-4

#define NBLK 256          // one block per CU (cooperative, co-resident)
#define BSIZE 1024        // 16 waves = 4 waves/SIMD
#define QPW 8             // queries per wave-subgroup (8-way ILP, proven)

struct IcpCtl {
  double st[12];    // Rc row-major [0..8], tc [9..11]
  int done;
  unsigned gen;     // published-iteration counter (solver bumps)
  unsigned ticket;  // cumulative arrival counter (target = NBLK*(it+1))
};

#define AT_LD(p)    __hip_atomic_load((p), __ATOMIC_RELAXED, __HIP_MEMORY_SCOPE_AGENT)
#define AT_ST(p, v) __hip_atomic_store((p), (v), __ATOMIC_RELAXED, __HIP_MEMORY_SCOPE_AGENT)

// ---------------------------------------------------------------------------
// prep: p2aug = (x,y,z,|b|^2) float4; ctl reset (runs every replay)
// ---------------------------------------------------------------------------
__global__ __launch_bounds__(256) void icp_prep(const float* __restrict__ p2,
                                                float4* __restrict__ p2aug,
                                                IcpCtl* __restrict__ ctl) {
  int t = blockIdx.x * 256 + threadIdx.x;   // grid covers exactly N_PTS
  float x = p2[3*t], y = p2[3*t+1], z = p2[3*t+2];
  p2aug[t] = make_float4(x, y, z, fmaf(x, x, fmaf(y, y, z*z)));
  if (t == 0) {
    ctl->done = 0; ctl->gen = 0u; ctl->ticket = 0u;
    #pragma unroll
    for (int i = 0; i < 12; ++i) ctl->st[i] = 0.0;
  }
}

// ---------------------------------------------------------------------------
// Register-only 3x3 Kabsch from raw sums (no runtime-indexed arrays).
// s[0]=sum dmin, s[1..3]=sum src, s[4..6]=sum dst, s[7..15]=sum src_i*dst_j.
// R = V diag(1,1,detV) U~^T (right-handed U~) == reference's sign-fixed SVD.
// ---------------------------------------------------------------------------
__device__ __forceinline__ void kabsch_solve(const double* s, double* R, double* T) {
  const double n = (double)N_PTS;
  const double c1x = s[1]/n, c1y = s[2]/n, c1z = s[3]/n;
  const double c2x = s[4]/n, c2y = s[5]/n, c2z = s[6]/n;
  const double h00 = s[7]  - n*c1x*c2x, h01 = s[8]  - n*c1x*c2y, h02 = s[9]  - n*c1x*c2z;
  const double h10 = s[10] - n*c1y*c2x, h11 = s[11] - n*c1y*c2y, h12 = s[12] - n*c1y*c2z;
  const double h20 = s[13] - n*c1z*c2x, h21 = s[14] - n*c1z*c2y, h22 = s[15] - n*c1z*c2z;

  double a00 = h00*h00 + h10*h10 + h20*h20;
  double a01 = h00*h01 + h10*h11 + h20*h21;
  double a02 = h00*h02 + h10*h12 + h20*h22;
  double a11 = h01*h01 + h11*h11 + h21*h21;
  double a12 = h01*h02 + h11*h12 + h21*h22;
  double a22 = h02*h02 + h12*h12 + h22*h22;

  double v00=1.0, v01=0.0, v02=0.0;
  double v10=0.0, v11=1.0, v12=0.0;
  double v20=0.0, v21=0.0, v22=1.0;

#define ROT3(app, aqq, apq, arp, arq, vpa, vqa, vpb, vqb, vpc, vqc)              \
  {                                                                              \
    double apq_ = apq;                                                           \
    if (fabs(apq_) > 1e-300) {                                                   \
      double tau = (aqq - app) / (2.0 * apq_);                                   \
      double tt  = (tau >= 0.0 ? 1.0 : -1.0) / (fabs(tau) + sqrt(1.0 + tau*tau));\
      double c_  = 1.0 / sqrt(1.0 + tt*tt), sn = tt * c_;                        \
      app -= tt * apq_;  aqq += tt * apq_;  apq = 0.0;                           \
      double t1 = arp, t2 = arq;                                                 \
      arp = c_*t1 - sn*t2;  arq = sn*t1 + c_*t2;                                 \
      t1 = vpa; t2 = vqa; vpa = c_*t1 - sn*t2; vqa = sn*t1 + c_*t2;              \
      t1 = vpb; t2 = vqb; vpb = c_*t1 - sn*t2; vqb = sn*t1 + c_*t2;              \
      t1 = vpc; t2 = vqc; vpc = c_*t1 - sn*t2; vqc = sn*t1 + c_*t2;              \
    }                                                                            \
  }

  #pragma unroll
  for (int sweep = 0; sweep < 6; ++sweep) {
    ROT3(a00, a11, a01, a02, a12, v00, v01, v10, v11, v20, v21);  // (0,1)
    ROT3(a00, a22, a02, a01, a12, v00, v02, v10, v12, v20, v22);  // (0,2)
    ROT3(a11, a22, a12, a01, a02, v01, v02, v11, v12, v21, v22);  // (1,2)
  }
#undef ROT3

  double l0 = a00, l1 = a11, l2 = a22;
  double e0x=v00, e0y=v10, e0z=v20;
  double e1x=v01, e1y=v11, e1z=v21;
  double e2x=v02, e2y=v12, e2z=v22;
#define CSWAP(la, lb, xa, ya, za, xb, yb, zb)                                    \
  if (lb > la) { double t_;                                                      \
    t_ = la; la = lb; lb = t_;  t_ = xa; xa = xb; xb = t_;                       \
    t_ = ya; ya = yb; yb = t_;  t_ = za; za = zb; zb = t_; }
  CSWAP(l0, l1, e0x, e0y, e0z, e1x, e1y, e1z);
  CSWAP(l0, l2, e0x, e0y, e0z, e2x, e2y, e2z);
  CSWAP(l1, l2, e1x, e1y, e1z, e2x, e2y, e2z);
#undef CSWAP

  double detV = e0x*(e1y*e2z - e1z*e2y) - e0y*(e1x*e2z - e1z*e2x)
              + e0z*(e1x*e2y - e1y*e2x);
  const double dsg = (detV >= 0.0) ? 1.0 : -1.0;

  double u0x = h00*e0x + h01*e0y + h02*e0z;
  double u0y = h10*e0x + h11*e0y + h12*e0z;
  double u0z = h20*e0x + h21*e0y + h22*e0z;
  double n0 = sqrt(u0x*u0x + u0y*u0y + u0z*u0z);
  if (!(n0 > 1e-150)) {
    R[0]=1.0; R[1]=0.0; R[2]=0.0; R[3]=0.0; R[4]=1.0; R[5]=0.0;
    R[6]=0.0; R[7]=0.0; R[8]=1.0;
    T[0]=c2x-c1x; T[1]=c2y-c1y; T[2]=c2z-c1z;
    return;
  }
  u0x /= n0; u0y /= n0; u0z /= n0;
  double u1x = h00*e1x + h01*e1y + h02*e1z;
  double u1y = h10*e1x + h11*e1y + h12*e1z;
  double u1z = h20*e1x + h21*e1y + h22*e1z;
  const double d10 = u1x*u0x + u1y*u0y + u1z*u0z;
  u1x -= d10*u0x; u1y -= d10*u0y; u1z -= d10*u0z;
  double n1 = sqrt(u1x*u1x + u1y*u1y + u1z*u1z);
  if (!(n1 > 1e-150)) {
    R[0]=1.0; R[1]=0.0; R[2]=0.0; R[3]=0.0; R[4]=1.0; R[5]=0.0;
    R[6]=0.0; R[7]=0.0; R[8]=1.0;
    T[0]=c2x-c1x; T[1]=c2y-c1y; T[2]=c2z-c1z;
    return;
  }
  u1x /= n1; u1y /= n1; u1z /= n1;
  const double u2x = u0y*u1z - u0z*u1y;
  const double u2y = u0z*u1x - u0x*u1z;
  const double u2z = u0x*u1y - u0y*u1x;

  R[0] = e0x*u0x + e1x*u1x + dsg*e2x*u2x;
  R[1] = e0x*u0y + e1x*u1y + dsg*e2x*u2y;
  R[2] = e0x*u0z + e1x*u1z + dsg*e2x*u2z;
  R[3] = e0y*u0x + e1y*u1x + dsg*e2y*u2x;
  R[4] = e0y*u0y + e1y*u1y + dsg*e2y*u2y;
  R[5] = e0y*u0z + e1y*u1z + dsg*e2y*u2z;
  R[6] = e0z*u0x + e1z*u1x + dsg*e2z*u2x;
  R[7] = e0z*u0y + e1z*u1y + dsg*e2z*u2y;
  R[8] = e0z*u0z + e1z*u1z + dsg*e2z*u2z;
  T[0] = c2x - (R[0]*c1x + R[1]*c1y + R[2]*c1z);
  T[1] = c2y - (R[3]*c1x + R[4]*c1y + R[5]*c1z);
  T[2] = c2z - (R[6]*c1x + R[7]*c1y + R[8]*c1z);
}

// ---------------------------------------------------------------------------
// Persistent cooperative kernel: entire ICP loop, one dispatch.
// Candidates staged in LDS ONCE; queries in registers ONCE. Per iteration:
// NN -> butterfly -> pair sums -> 16 relaxed atomic STORES (distinct addrs)
// -> vmcnt(0) -> relaxed cumulative ticket. Block 0 = solver: relaxed-poll
// ticket, gather partials via relaxed atomic loads, register Kabsch, write
// out, publish state via relaxed atomic stores + vmcnt(0) + gen bump.
// Others relaxed-poll gen. ZERO acquire/release -> no cache-invalidate
// storms (R4's failure mode). Coherence-point ordering via vmcnt.
// ---------------------------------------------------------------------------
__global__ __launch_bounds__(BSIZE, 1) void icp_run(const float* __restrict__ p1,
                                                    const float4* __restrict__ p2aug,
                                                    IcpCtl* __restrict__ ctl,
                                                    double* __restrict__ parts,
                                                    float* __restrict__ out) {
  __shared__ float4 cand[N_PTS];            // 128 KiB, persists all iterations
  __shared__ unsigned long long pkbuf[32][4];
  __shared__ float4 qlds[32];
  __shared__ double pairbuf[32][17];        // +1 pad
  __shared__ double redbuf[64];
  __shared__ double stLds[12];
  __shared__ int sdone;

  const int tid  = threadIdx.x;
  const int lane = tid & 63;
  const int w    = tid >> 6;
  const int g    = w >> 2;                  // query subgroup 0..3
  const int s    = w & 3;                   // candidate slice 0..3
  const int bid  = blockIdx.x;

  // ---- stage ALL candidates into LDS once ----
  #pragma unroll
  for (int k = 0; k < 8; ++k) {
    const int i = (k << 10) + tid;
    cand[i] = p2aug[i];
  }
  // ---- load this subgroup's 8 queries once (fp32 registers) ----
  const int qbase = (bid << 5) + (g << 3);
  float Xf[QPW], Yf[QPW], Zf[QPW];
  #pragma unroll
  for (int j = 0; j < QPW; ++j) {
    const int q = qbase + j;
    Xf[j] = p1[3*q]; Yf[j] = p1[3*q+1]; Zf[j] = p1[3*q+2];
  }
  __syncthreads();

  // cumulative transform state (identity at iteration 0)
  double R0=1.0, R1=0.0, R2=0.0, R3=0.0, R4=1.0, R5=0.0,
         R6=0.0, R7=0.0, R8=1.0, T0=0.0, T1=0.0, T2=0.0;
  double errPrev = 0.0;                     // meaningful on solver tid0 only

  for (int it = 0; it < ICP_STEPS; ++it) {
    // ---- query transforms (fp32-rounded, matches ref pc) ----
    float axv[QPW], ayv[QPW], azv[QPW], best[QPW];
    int bidx[QPW];
    #pragma unroll
    for (int j = 0; j < QPW; ++j) {
      const double X = (double)Xf[j], Y = (double)Yf[j], Z = (double)Zf[j];
      const float qx = (float)(R0*X + R1*Y + R2*Z + T0);
      const float qy = (float)(R3*X + R4*Y + R5*Z + T1);
      const float qz = (float)(R6*X + R7*Y + R8*Z + T2);
      axv[j] = -2.f*qx; ayv[j] = -2.f*qy; azv[j] = -2.f*qz;
      best[j] = __builtin_inff(); bidx[j] = 0;
      if (s == 0 && lane == 0) qlds[(g << 3) + j] = make_float4(qx, qy, qz, 0.f);
    }
    __syncthreads();                        // qlds visible; prev phase done

    // ---- NN scan: slice s = cands [s*2048, s*2048+2048) ----
    const int cb = s << 11;
    #pragma unroll 8
    for (int kk = 0; kk < 32; ++kk) {
      const int cidx = cb + (kk << 6) + lane;
      float4 c = cand[cidx];                // ds_read_b128, conflict-free
      #pragma unroll
      for (int j = 0; j < QPW; ++j) {
        float d = fmaf(axv[j], c.x, fmaf(ayv[j], c.y, fmaf(azv[j], c.z, c.w)));
        if (d < best[j]) { best[j] = d; bidx[j] = cidx; }
      }
    }

    // ---- cross-lane argmin: packed (ordered-dist, idx) u64 butterfly ----
    unsigned long long pk[QPW];
    #pragma unroll
    for (int j = 0; j < QPW; ++j) {
      unsigned u = __float_as_uint(best[j]);
      u ^= (unsigned)((int)u >> 31) | 0x80000000u;   // monotone float->uint
      pk[j] = ((unsigned long long)u << 32) | (unsigned)bidx[j];
    }
    #pragma unroll
    for (int j = 0; j < QPW; ++j) {
      #pragma unroll
      for (int o = 1; o < 64; o <<= 1) {
        unsigned long long other = __shfl_xor(pk[j], o, 64);
        pk[j] = (other < pk[j]) ? other : pk[j];
      }
    }
    if (lane == 0) {
      #pragma unroll
      for (int j = 0; j < QPW; ++j)
        pkbuf[(g << 3) + j][s] = pk[j];
    }
    __syncthreads();

    // ---- combine 4 slices + pair sums: tid<32, all static indexing ----
    if (tid < 32) {
      unsigned long long m = pkbuf[tid][0];
      unsigned long long m1 = pkbuf[tid][1]; m = (m1 < m) ? m1 : m;
      unsigned long long m2 = pkbuf[tid][2]; m = (m2 < m) ? m2 : m;
      unsigned long long m3 = pkbuf[tid][3]; m = (m3 < m) ? m3 : m;
      const unsigned idx = (unsigned)(m & 0xffffffffull);
      const float4 q4 = qlds[tid];
      const float4 b4 = cand[idx];
      const double ax = q4.x, ay = q4.y, az = q4.z;
      const double bx = b4.x, by = b4.y, bz = b4.z;
      const double d2 = (ax*ax + ay*ay + az*az) + (bx*bx + by*by + bz*bz)
                      - 2.0*(ax*bx + ay*by + az*bz);
      pairbuf[tid][0]  = sqrt(fmax(d2, 1e-12));
      pairbuf[tid][1]  = ax;    pairbuf[tid][2]  = ay;    pairbuf[tid][3]  = az;
      pairbuf[tid][4]  = bx;    pairbuf[tid][5]  = by;    pairbuf[tid][6]  = bz;
      pairbuf[tid][7]  = ax*bx; pairbuf[tid][8]  = ax*by; pairbuf[tid][9]  = ax*bz;
      pairbuf[tid][10] = ay*bx; pairbuf[tid][11] = ay*by; pairbuf[tid][12] = ay*bz;
      pairbuf[tid][13] = az*bx; pairbuf[tid][14] = az*by; pairbuf[tid][15] = az*bz;
    }
    __syncthreads();

    // ---- 16 partials -> relaxed atomic STORES (distinct addresses) ----
    if (tid < 16) {
      double ssum = 0.0;
      #pragma unroll
      for (int i = 0; i < 32; ++i) ssum += pairbuf[i][tid];
      AT_ST(&parts[(bid << 4) + tid], ssum);
    }
    if (tid == 0) {
      // wave 0 issued the stores; wait their coherence-point ACK, then arrive
      asm volatile("s_waitcnt vmcnt(0)" ::: "memory");
      __hip_atomic_fetch_add(&ctl->ticket, 1u,
                             __ATOMIC_RELAXED, __HIP_MEMORY_SCOPE_AGENT);
    }

    if (bid == 0) {
      // ---------------- solver block ----------------
      if (tid == 0) {
        const unsigned target = (unsigned)NBLK * (unsigned)(it + 1);
        while (AT_LD(&ctl->ticket) < target) __builtin_amdgcn_s_sleep(8);
      }
      __syncthreads();
      // gather 256x16 partials (relaxed atomic loads, distinct addresses)
      double vv[16];
      if (tid < 256) {
        #pragma unroll
        for (int c = 0; c < 16; ++c) vv[c] = AT_LD(&parts[(tid << 4) + c]);
      } else {
        #pragma unroll
        for (int c = 0; c < 16; ++c) vv[c] = 0.0;
      }
      if (w < 4) {
        #pragma unroll
        for (int q = 0; q < 16; ++q) {
          double x = vv[q];
          for (int o = 32; o > 0; o >>= 1) x += __shfl_down(x, o, 64);
          if (lane == 0) redbuf[w*16 + q] = x;
        }
      }
      __syncthreads();
      if (tid == 0) {
        double sm[16];
        #pragma unroll
        for (int i = 0; i < 16; ++i)
          sm[i] = redbuf[i] + redbuf[16+i] + redbuf[32+i] + redbuf[48+i];
        double Rk[9], Tk[3];
        kabsch_solve(sm, Rk, Tk);
        // compose: (Rk*Rc, Rk*tc + Tk)
        double Rc[9] = {R0,R1,R2,R3,R4,R5,R6,R7,R8};
        double tc[3] = {T0,T1,T2};
        double Rn[9], tn[3];
        #pragma unroll
        for (int i = 0; i < 3; ++i) {
          #pragma unroll
          for (int j = 0; j < 3; ++j)
            Rn[3*i+j] = Rk[3*i+0]*Rc[0+j] + Rk[3*i+1]*Rc[3+j] + Rk[3*i+2]*Rc[6+j];
          tn[i] = Rk[3*i+0]*tc[0] + Rk[3*i+1]*tc[1] + Rk[3*i+2]*tc[2] + Tk[i];
        }
        const int dn = (fabs(errPrev - sm[0]) < ICP_TOL) ? 1 : 0;
        errPrev = sm[0];
        // out = [Rc | tc] 3x4 (update applies at the detecting step, per ref)
        #pragma unroll
        for (int i = 0; i < 3; ++i) {
          out[4*i + 0] = (float)Rn[3*i + 0];
          out[4*i + 1] = (float)Rn[3*i + 1];
          out[4*i + 2] = (float)Rn[3*i + 2];
          out[4*i + 3] = (float)tn[i];
        }
        // publish state + done, then bump gen after ACK
        #pragma unroll
        for (int i = 0; i < 9; ++i) AT_ST(&ctl->st[i], Rn[i]);
        #pragma unroll
        for (int i = 0; i < 3; ++i) AT_ST(&ctl->st[9 + i], tn[i]);
        __hip_atomic_store(&ctl->done, dn, __ATOMIC_RELAXED, __HIP_MEMORY_SCOPE_AGENT);
        asm volatile("s_waitcnt vmcnt(0)" ::: "memory");
        AT_ST(&ctl->gen, (unsigned)(it + 1));
        // local broadcast for own block
        #pragma unroll
        for (int i = 0; i < 9; ++i) stLds[i] = Rn[i];
        stLds[9] = tn[0]; stLds[10] = tn[1]; stLds[11] = tn[2];
        sdone = dn;
      }
      __syncthreads();
    } else {
      // ---------------- poller blocks ----------------
      if (tid == 0) {
        while (AT_LD(&ctl->gen) < (unsigned)(it + 1)) __builtin_amdgcn_s_sleep(8);
      }
      __syncthreads();
      if (tid < 12) stLds[tid] = AT_LD(&ctl->st[tid]);
      if (tid == 12)
        sdone = __hip_atomic_load(&ctl->done, __ATOMIC_RELAXED, __HIP_MEMORY_SCOPE_AGENT);
      __syncthreads();
    }

    // ---- adopt new state; frozen -> break (uniform everywhere) ----
    R0 = stLds[0]; R1 = stLds[1]; R2 = stLds[2];
    R3 = stLds[3]; R4 = stLds[4]; R5 = stLds[5];
    R6 = stLds[6]; R7 = stLds[7]; R8 = stLds[8];
    T0 = stLds[9]; T1 = stLds[10]; T2 = stLds[11];
    if (sdone) break;
  }
}

// ---------------------------------------------------------------------------
extern "C" void kernel_launch(void* const* d_in, const int* in_sizes, int n_in,
                              void* d_out, int out_size, void* d_ws, size_t ws_size,
                              hipStream_t stream) {
  const float* p1 = (const float*)d_in[0];
  const float* p2 = (const float*)d_in[1];
  float* out = (float*)d_out;

  char* ws = (char*)d_ws;
  float4* p2aug = (float4*)ws;                       // 128 KiB
  IcpCtl* ctl   = (IcpCtl*)(ws + 128*1024);          // ~112 B
  double* parts = (double*)(ws + 128*1024 + 512);    // 32 KiB (256 x 16 f64)

  icp_prep<<<N_PTS/256, 256, 0, stream>>>(p2, p2aug, ctl);

  void* args[] = { (void*)&p1, (void*)&p2aug, (void*)&ctl, (void*)&parts, (void*)&out };
  hipLaunchCooperativeKernel((const void*)icp_run, dim3(NBLK), dim3(BSIZE),
                             args, 0, stream);
}

// Round 13
// 804.105 us; speedup vs baseline: 1.1142x; 1.1142x over previous
//
#include <hip/hip_runtime.h>
#include <math.h>

#define N_PTS 8192
#define ICP_STEPS 21      // STEPLIM + 1 scan iterations
#define ICP_TOL 1e-4

// NN geometry (R2-proven): 4 query-groups (2048 q) x 64 cand-slices (128 c)
#define NN_QPT 8          // queries per thread (8-way ILP)
#define NN_CSL 128        // candidates per slice
#define NN_BLOCKS 256
#define SOLVE_T 512       // 8 waves

struct IcpCtl {
  double err;
  double Rc[9];     // cumulative rotation (row-major): pc = Rc*p1 + tc
  double tc[3];
  int done;
};

// ---------------------------------------------------------------------------
// prep: p2aug = (x,y,z,|b|^2); nn sentinels; ctl reset (runs every replay)
// ---------------------------------------------------------------------------
__global__ __launch_bounds__(256) void icp_prep(const float* __restrict__ p2,
                                                float4* __restrict__ p2aug,
                                                unsigned long long* __restrict__ nn,
                                                IcpCtl* __restrict__ ctl) {
  int t = blockIdx.x * 256 + threadIdx.x;   // grid covers exactly N_PTS
  float x = p2[3*t], y = p2[3*t+1], z = p2[3*t+2];
  p2aug[t] = make_float4(x, y, z, fmaf(x, x, fmaf(y, y, z*z)));
  nn[t] = ~0ull;
  if (t == 0) {
    ctl->err = 0.0; ctl->done = 0;
    #pragma unroll
    for (int i = 0; i < 9; ++i) ctl->Rc[i] = (i % 4 == 0) ? 1.0 : 0.0;
    ctl->tc[0] = ctl->tc[1] = ctl->tc[2] = 0.0;
  }
}

// ---------------------------------------------------------------------------
// NN search (R2-proven geometry + cumulative transform). Each thread owns 8
// queries, scans 128 LDS-staged candidates. Cross-block argmin via relaxed
// memory-side atomicMin on packed (ordered-float(d2'), idx) u64 -> lowest
// distance then lowest index (jnp.argmin tie semantics).
// d2' = |b|^2 - 2 a.b (|a|^2 dropped: argmin-invariant per query).
// ---------------------------------------------------------------------------
__global__ __launch_bounds__(256) void icp_nn(const float* __restrict__ p1,
                                              const float4* __restrict__ p2aug,
                                              unsigned long long* __restrict__ nn,
                                              const IcpCtl* __restrict__ ctl) {
  if (ctl->done) return;                     // uniform across grid
  __shared__ float4 cand[NN_CSL];
  const int tid = threadIdx.x;
  const int qg  = blockIdx.x >> 6;           // 0..3
  const int cs  = blockIdx.x & 63;           // 0..63
  const int c0  = cs * NN_CSL;
  if (tid < NN_CSL) cand[tid] = p2aug[c0 + tid];

  const double R0 = ctl->Rc[0], R1 = ctl->Rc[1], R2 = ctl->Rc[2];
  const double R3 = ctl->Rc[3], R4 = ctl->Rc[4], R5 = ctl->Rc[5];
  const double R6 = ctl->Rc[6], R7 = ctl->Rc[7], R8 = ctl->Rc[8];
  const double T0 = ctl->tc[0], T1 = ctl->tc[1], T2 = ctl->tc[2];

  float ax[NN_QPT], ay[NN_QPT], az[NN_QPT], best[NN_QPT];
  int bidx[NN_QPT];
  const int qbase = (qg << 11) + tid;        // qg*2048 + tid
  #pragma unroll
  for (int j = 0; j < NN_QPT; ++j) {
    const int q = qbase + (j << 8);
    const double X = (double)p1[3*q], Y = (double)p1[3*q+1], Z = (double)p1[3*q+2];
    const float qx = (float)(R0*X + R1*Y + R2*Z + T0);  // fp32-rounded (ref pc)
    const float qy = (float)(R3*X + R4*Y + R5*Z + T1);
    const float qz = (float)(R6*X + R7*Y + R8*Z + T2);
    ax[j] = -2.f*qx; ay[j] = -2.f*qy; az[j] = -2.f*qz;
    best[j] = __builtin_inff(); bidx[j] = 0;
  }
  __syncthreads();

  #pragma unroll 4
  for (int i = 0; i < NN_CSL; ++i) {
    float4 c = cand[i];
    #pragma unroll
    for (int j = 0; j < NN_QPT; ++j) {
      float d = fmaf(ax[j], c.x, fmaf(ay[j], c.y, fmaf(az[j], c.z, c.w)));
      if (d < best[j]) { best[j] = d; bidx[j] = c0 + i; }
    }
  }
  #pragma unroll
  for (int j = 0; j < NN_QPT; ++j) {
    unsigned u = __float_as_uint(best[j]);
    u ^= (unsigned)((int)u >> 31) | 0x80000000u;   // monotone float->uint map
    atomicMin(nn + qbase + (j << 8),
              ((unsigned long long)u << 32) | (unsigned)bidx[j]);
  }
}

// ---------------------------------------------------------------------------
// Register-only 3x3 Kabsch from raw sums (no runtime-indexed arrays).
// s[0]=sum dmin, s[1..3]=sum src, s[4..6]=sum dst, s[7..15]=sum src_i*dst_j.
// R = V diag(1,1,detV) U~^T (right-handed U~) == reference's sign-fixed SVD.
// ---------------------------------------------------------------------------
__device__ __forceinline__ void kabsch_solve(const double* s, double* R, double* T) {
  const double n = (double)N_PTS;
  const double c1x = s[1]/n, c1y = s[2]/n, c1z = s[3]/n;
  const double c2x = s[4]/n, c2y = s[5]/n, c2z = s[6]/n;
  const double h00 = s[7]  - n*c1x*c2x, h01 = s[8]  - n*c1x*c2y, h02 = s[9]  - n*c1x*c2z;
  const double h10 = s[10] - n*c1y*c2x, h11 = s[11] - n*c1y*c2y, h12 = s[12] - n*c1y*c2z;
  const double h20 = s[13] - n*c1z*c2x, h21 = s[14] - n*c1z*c2y, h22 = s[15] - n*c1z*c2z;

  double a00 = h00*h00 + h10*h10 + h20*h20;
  double a01 = h00*h01 + h10*h11 + h20*h21;
  double a02 = h00*h02 + h10*h12 + h20*h22;
  double a11 = h01*h01 + h11*h11 + h21*h21;
  double a12 = h01*h02 + h11*h12 + h21*h22;
  double a22 = h02*h02 + h12*h12 + h22*h22;

  double v00=1.0, v01=0.0, v02=0.0;
  double v10=0.0, v11=1.0, v12=0.0;
  double v20=0.0, v21=0.0, v22=1.0;

#define ROT3(app, aqq, apq, arp, arq, vpa, vqa, vpb, vqb, vpc, vqc)              \
  {                                                                              \
    double apq_ = apq;                                                           \
    if (fabs(apq_) > 1e-300) {                                                   \
      double tau = (aqq - app) / (2.0 * apq_);                                   \
      double tt  = (tau >= 0.0 ? 1.0 : -1.0) / (fabs(tau) + sqrt(1.0 + tau*tau));\
      double c_  = 1.0 / sqrt(1.0 + tt*tt), sn = tt * c_;                        \
      app -= tt * apq_;  aqq += tt * apq_;  apq = 0.0;                           \
      double t1 = arp, t2 = arq;                                                 \
      arp = c_*t1 - sn*t2;  arq = sn*t1 + c_*t2;                                 \
      t1 = vpa; t2 = vqa; vpa = c_*t1 - sn*t2; vqa = sn*t1 + c_*t2;              \
      t1 = vpb; t2 = vqb; vpb = c_*t1 - sn*t2; vqb = sn*t1 + c_*t2;              \
      t1 = vpc; t2 = vqc; vpc = c_*t1 - sn*t2; vqc = sn*t1 + c_*t2;              \
    }                                                                            \
  }

  #pragma unroll
  for (int sweep = 0; sweep < 6; ++sweep) {
    ROT3(a00, a11, a01, a02, a12, v00, v01, v10, v11, v20, v21);  // (0,1)
    ROT3(a00, a22, a02, a01, a12, v00, v02, v10, v12, v20, v22);  // (0,2)
    ROT3(a11, a22, a12, a01, a02, v01, v02, v11, v12, v21, v22);  // (1,2)
  }
#undef ROT3

  double l0 = a00, l1 = a11, l2 = a22;
  double e0x=v00, e0y=v10, e0z=v20;
  double e1x=v01, e1y=v11, e1z=v21;
  double e2x=v02, e2y=v12, e2z=v22;
#define CSWAP(la, lb, xa, ya, za, xb, yb, zb)                                    \
  if (lb > la) { double t_;                                                      \
    t_ = la; la = lb; lb = t_;  t_ = xa; xa = xb; xb = t_;                       \
    t_ = ya; ya = yb; yb = t_;  t_ = za; za = zb; zb = t_; }
  CSWAP(l0, l1, e0x, e0y, e0z, e1x, e1y, e1z);
  CSWAP(l0, l2, e0x, e0y, e0z, e2x, e2y, e2z);
  CSWAP(l1, l2, e1x, e1y, e1z, e2x, e2y, e2z);
#undef CSWAP

  double detV = e0x*(e1y*e2z - e1z*e2y) - e0y*(e1x*e2z - e1z*e2x)
              + e0z*(e1x*e2y - e1y*e2x);
  const double dsg = (detV >= 0.0) ? 1.0 : -1.0;

  double u0x = h00*e0x + h01*e0y + h02*e0z;
  double u0y = h10*e0x + h11*e0y + h12*e0z;
  double u0z = h20*e0x + h21*e0y + h22*e0z;
  double n0 = sqrt(u0x*u0x + u0y*u0y + u0z*u0z);
  if (!(n0 > 1e-150)) {
    R[0]=1.0; R[1]=0.0; R[2]=0.0; R[3]=0.0; R[4]=1.0; R[5]=0.0;
    R[6]=0.0; R[7]=0.0; R[8]=1.0;
    T[0]=c2x-c1x; T[1]=c2y-c1y; T[2]=c2z-c1z;
    return;
  }
  u0x /= n0; u0y /= n0; u0z /= n0;
  double u1x = h00*e1x + h01*e1y + h02*e1z;
  double u1y = h10*e1x + h11*e1y + h12*e1z;
  double u1z = h20*e1x + h21*e1y + h22*e1z;
  const double d10 = u1x*u0x + u1y*u0y + u1z*u0z;
  u1x -= d10*u0x; u1y -= d10*u0y; u1z -= d10*u0z;
  double n1 = sqrt(u1x*u1x + u1y*u1y + u1z*u1z);
  if (!(n1 > 1e-150)) {
    R[0]=1.0; R[1]=0.0; R[2]=0.0; R[3]=0.0; R[4]=1.0; R[5]=0.0;
    R[6]=0.0; R[7]=0.0; R[8]=1.0;
    T[0]=c2x-c1x; T[1]=c2y-c1y; T[2]=c2z-c1z;
    return;
  }
  u1x /= n1; u1y /= n1; u1z /= n1;
  const double u2x = u0y*u1z - u0z*u1y;
  const double u2y = u0z*u1x - u0x*u1z;
  const double u2z = u0x*u1y - u0y*u1x;

  R[0] = e0x*u0x + e1x*u1x + dsg*e2x*u2x;
  R[1] = e0x*u0y + e1x*u1y + dsg*e2x*u2y;
  R[2] = e0x*u0z + e1x*u1z + dsg*e2x*u2z;
  R[3] = e0y*u0x + e1y*u1x + dsg*e2y*u2x;
  R[4] = e0y*u0y + e1y*u1y + dsg*e2y*u2y;
  R[5] = e0y*u0z + e1y*u1z + dsg*e2y*u2z;
  R[6] = e0z*u0x + e1z*u1x + dsg*e2z*u2x;
  R[7] = e0z*u0y + e1z*u1y + dsg*e2z*u2y;
  R[8] = e0z*u0z + e1z*u1z + dsg*e2z*u2z;
  T[0] = c2x - (R[0]*c1x + R[1]*c1y + R[2]*c1z);
  T[1] = c2y - (R[3]*c1x + R[4]*c1y + R[5]*c1z);
  T[2] = c2z - (R[6]*c1x + R[7]*c1y + R[8]*c1z);
}

// ---------------------------------------------------------------------------
// solve (1 block x 512 threads): gather 8192 matched pairs (16 rounds),
// reset nn sentinels inline, f64 sums -> shuffle reduce -> register Kabsch
// on tid0 -> compose, done-logic, write out + ctl. Kernel-boundary coherence.
// ---------------------------------------------------------------------------
__global__ __launch_bounds__(SOLVE_T, 1) void icp_solve(
    const float* __restrict__ p1, const float4* __restrict__ p2aug,
    unsigned long long* __restrict__ nn, IcpCtl* __restrict__ ctl,
    float* __restrict__ out) {
  if (ctl->done) return;
  __shared__ double lds[8 * 16];
  __shared__ double tot[16];
  const int tid  = threadIdx.x;
  const int lane = tid & 63;
  const int w    = tid >> 6;

  const double R0 = ctl->Rc[0], R1 = ctl->Rc[1], R2 = ctl->Rc[2];
  const double R3 = ctl->Rc[3], R4 = ctl->Rc[4], R5 = ctl->Rc[5];
  const double R6 = ctl->Rc[6], R7 = ctl->Rc[7], R8 = ctl->Rc[8];
  const double T0 = ctl->tc[0], T1 = ctl->tc[1], T2 = ctl->tc[2];

  double v0=0,v1=0,v2=0,v3=0,v4=0,v5=0,v6=0,v7=0,
         v8=0,v9=0,v10=0,v11=0,v12=0,v13=0,v14=0,v15=0;

  for (int k = 0; k < 16; ++k) {
    const int i = (k << 9) + tid;
    const unsigned idx = (unsigned)(nn[i] & 0xffffffffull);
    nn[i] = ~0ull;                          // reset for next iteration
    const double X = (double)p1[3*i], Y = (double)p1[3*i+1], Z = (double)p1[3*i+2];
    // fp32-rounded source position (bit-identical to what NN used)
    const float sxf = (float)(R0*X + R1*Y + R2*Z + T0);
    const float syf = (float)(R3*X + R4*Y + R5*Z + T1);
    const float szf = (float)(R6*X + R7*Y + R8*Z + T2);
    const float4 b4 = p2aug[idx];
    const double ax = sxf, ay = syf, az = szf;
    const double bx = b4.x, by = b4.y, bz = b4.z;
    const double d2 = (ax*ax + ay*ay + az*az) + (bx*bx + by*by + bz*bz)
                    - 2.0*(ax*bx + ay*by + az*bz);
    v0  += sqrt(fmax(d2, 1e-12));
    v1  += ax;    v2  += ay;    v3  += az;
    v4  += bx;    v5  += by;    v6  += bz;
    v7  += ax*bx; v8  += ax*by; v9  += ax*bz;
    v10 += ay*bx; v11 += ay*by; v12 += ay*bz;
    v13 += az*bx; v14 += az*by; v15 += az*bz;
  }

  // 8-wave reduce: shuffle within wave, lane0 -> lds, tid<16 sums 8 rows
#define WRED(val, q)                                                           \
  { double x = (val);                                                          \
    for (int o = 32; o > 0; o >>= 1) x += __shfl_down(x, o, 64);               \
    if (lane == 0) lds[w*16 + (q)] = x; }
  WRED(v0,0) WRED(v1,1) WRED(v2,2) WRED(v3,3) WRED(v4,4) WRED(v5,5)
  WRED(v6,6) WRED(v7,7) WRED(v8,8) WRED(v9,9) WRED(v10,10) WRED(v11,11)
  WRED(v12,12) WRED(v13,13) WRED(v14,14) WRED(v15,15)
#undef WRED
  __syncthreads();
  if (tid < 16) {
    double s = 0.0;
    #pragma unroll
    for (int r = 0; r < 8; ++r) s += lds[r*16 + tid];
    tot[tid] = s;
  }
  __syncthreads();

  if (tid == 0) {
    double sm[16];
    #pragma unroll
    for (int i = 0; i < 16; ++i) sm[i] = tot[i];
    double R[9], T[3];
    kabsch_solve(sm, R, T);
    // compose: pc_new = R*(Rc*p1 + tc) + T = (R*Rc)*p1 + (R*tc + T)
    double Rc[9] = {R0,R1,R2,R3,R4,R5,R6,R7,R8};
    double tc[3] = {T0,T1,T2};
    double Rn[9], tn[3];
    #pragma unroll
    for (int i = 0; i < 3; ++i) {
      #pragma unroll
      for (int j = 0; j < 3; ++j)
        Rn[3*i+j] = R[3*i+0]*Rc[0+j] + R[3*i+1]*Rc[3+j] + R[3*i+2]*Rc[6+j];
      tn[i] = R[3*i+0]*tc[0] + R[3*i+1]*tc[1] + R[3*i+2]*tc[2] + T[i];
    }
    #pragma unroll
    for (int i = 0; i < 9; ++i) ctl->Rc[i] = Rn[i];
    #pragma unroll
    for (int i = 0; i < 3; ++i) ctl->tc[i] = tn[i];
    const double errnew = sm[0];            // B == 1
    ctl->done = (fabs(ctl->err - errnew) < ICP_TOL) ? 1 : 0;
    ctl->err  = errnew;
    // out = [Rc | tc] 3x4 (kabsch(p1, Rc*p1+tc) == (Rc,tc) exactly).
    #pragma unroll
    for (int i = 0; i < 3; ++i) {
      out[4*i + 0] = (float)Rn[3*i + 0];
      out[4*i + 1] = (float)Rn[3*i + 1];
      out[4*i + 2] = (float)Rn[3*i + 2];
      out[4*i + 3] = (float)tn[i];
    }
  }
}

// ---------------------------------------------------------------------------
extern "C" void kernel_launch(void* const* d_in, const int* in_sizes, int n_in,
                              void* d_out, int out_size, void* d_ws, size_t ws_size,
                              hipStream_t stream) {
  const float* p1 = (const float*)d_in[0];
  const float* p2 = (const float*)d_in[1];
  float* out = (float*)d_out;

  char* ws = (char*)d_ws;
  float4* p2aug = (float4*)ws;                         // 128 KiB
  unsigned long long* nn = (unsigned long long*)(ws + 128*1024);  // 64 KiB
  IcpCtl* ctl = (IcpCtl*)(ws + 192*1024);              // ~112 B

  icp_prep<<<N_PTS/256, 256, 0, stream>>>(p2, p2aug, nn, ctl);
  for (int it = 0; it < ICP_STEPS; ++it) {
    icp_nn<<<NN_BLOCKS, 256, 0, stream>>>(p1, p2aug, nn, ctl);
    icp_solve<<<1, SOLVE_T, 0, stream>>>(p1, p2aug, nn, ctl, out);
  }
}